// Round 4
// baseline (2942.198 us; speedup 1.0000x reference)
//
#include <hip/hip_runtime.h>
#include <math.h>

// QuantumMambaSSMCore R10b: 16-wave shard (1024 thr), 1 amp/thread, 4 barriers/step.
//  - Index bits: lane={0,5,1,7,3,9} (wires 9,4,8,2,6,0), wave={4,8,6,2} (wires 5,1,3,7).
//  - Merged permute+wave-gates cover 4 wave wires: 16-coeff complex flat sum.
//    Coefficient table cwT[2][16][16] lives in LDS (wave-uniform broadcast reads)
//    to keep VGPR <= 128 (4 waves/SIMD).
//  - Phase B fully hoisted: S = sum_i K_i * tha_i with per-thread static K_i.
//    SIGN FIX vs R10: parity 1 -> +pch, parity 0 -> -pch (matches verified R9
//    flip = parity ^ 1 convention).
//  - Bank swizzle swz(j)=j^(((j>>5)&1)<<2); all merge read addresses precomputed.

#define PIF 3.14159265358979323846f

constexpr int NQ = 10, SEQ = 512, NB = 128, NTHR = 1024, RECF = 36;

// ---- QSVT phase masks (frame-0), verified in R7/R8/R9 ----
struct CTbl { int mz[4][NQ]; };
constexpr CTbl build_tbl() {
  CTbl t{};
  unsigned mrow[NQ];
  for (int b = 0; b < NQ; ++b) mrow[b] = 1u << b;
  for (int d = 0; d < 4; ++d) {
    for (int i = 0; i < NQ; ++i) t.mz[d][i] = (int)mrow[9 - i];
    for (int i = 0; i < NQ - 1; ++i) { int bc = 9 - i, bt = 8 - i; mrow[bt] ^= mrow[bc]; }
    mrow[9] ^= mrow[0];
  }
  return t;
}
constexpr CTbl CT = build_tbl();

// ---- index-permutation columns for the CNOT networks (circuit order) ----
struct PermCols { int c4[10]; int cL[10]; };
constexpr PermCols build_perms() {
  PermCols P{};
  for (int b = 0; b < 10; ++b) {
    int x = 1 << b;
    for (int d = 0; d < 4; ++d) {
      for (int i = 0; i < 9; ++i) { int bc = 9 - i, bt = 8 - i; if ((x >> bc) & 1) x ^= (1 << bt); }
      if (x & 1) x ^= (1 << 9);                       // ring CNOT: bc=0, bt=9
    }
    P.c4[b] = x;
    int y = 1 << b;
    for (int i = 0; i < 9; ++i) { int bc = 9 - i, bt = 8 - i; if ((y >> bc) & 1) y ^= (1 << bt); }
    P.cL[b] = y;
  }
  return P;
}
constexpr PermCols PC = build_perms();

constexpr int lanePart(int x)   { return ((x >> 0) & 1) | (((x >> 5) & 1) << 1) |
                                         (((x >> 1) & 1) << 2) | (((x >> 7) & 1) << 3) |
                                         (((x >> 3) & 1) << 4) | (((x >> 9) & 1) << 5); }
constexpr int wavePart16(int x) { return ((x >> 4) & 1) | (((x >> 8) & 1) << 1) |
                                         (((x >> 6) & 1) << 2) | (((x >> 2) & 1) << 3); }

typedef __attribute__((ext_vector_type(2))) float v2;

// wave-gate partner offsets: v bit0->phys4(16), bit1->phys8(256), bit2->phys6(64), bit3->phys2(4)
constexpr int VOFS16[16] = {0, 16, 256, 272, 64, 80, 320, 336,
                            4, 20, 260, 276, 68, 84, 324, 340};

// ---------------- cross-lane exchange helpers (within one wave) ----------------
template<int C>
__device__ __forceinline__ int dpp1(int x) {
  return __builtin_amdgcn_update_dpp(x, x, C, 0xF, 0xF, false);
}
template<int VL>
__device__ __forceinline__ int lxi(int x) {   // DPP xor-exchange, 1 <= VL <= 15
  if constexpr (VL == 1)  return dpp1<0xB1>(x);
  else if constexpr (VL == 2)  return dpp1<0x4E>(x);
  else if constexpr (VL == 3)  return dpp1<0x1B>(x);
  else if constexpr (VL <= 7) {
    constexpr int q = (VL & 3) ^ 3;
    int y = x;
    if constexpr (q == 1) y = dpp1<0xB1>(y);
    else if constexpr (q == 2) y = dpp1<0x4E>(y);
    else if constexpr (q == 3) y = dpp1<0x1B>(y);
    return dpp1<0x141>(y);                      // ^7
  } else if constexpr (VL >= 12) {
    constexpr int q = (VL & 3) ^ 3;
    int y = x;
    if constexpr (q == 1) y = dpp1<0xB1>(y);
    else if constexpr (q == 2) y = dpp1<0x4E>(y);
    else if constexpr (q == 3) y = dpp1<0x1B>(y);
    return dpp1<0x140>(y);                      // ^15
  } else {
    constexpr int a = VL & 3;
    int y = x;
    if constexpr (a == 1) y = dpp1<0xB1>(y);
    else if constexpr (a == 2) y = dpp1<0x4E>(y);
    else if constexpr (a == 3) y = dpp1<0x1B>(y);
    y = dpp1<0x141>(y);
    return dpp1<0x140>(y);
  }
}
template<int VL>
__device__ __forceinline__ float lx(float x) {
  if constexpr (VL == 0) return x;
  else if constexpr (VL & 32) {
    int addr = (((int)threadIdx.x & 63) ^ VL) << 2;
    return __int_as_float(__builtin_amdgcn_ds_bpermute(addr, __float_as_int(x)));
  } else if constexpr (VL & 16) {
    return __int_as_float(__builtin_amdgcn_ds_swizzle(__float_as_int(x), (VL << 10) | 0x1F));
  } else {
    return __int_as_float(lxi<VL>(__float_as_int(x)));
  }
}
__device__ __forceinline__ float rdl(float x, int l) {
  return __int_as_float(__builtin_amdgcn_readlane(__float_as_int(x), l));
}

// ---- LDS bank swizzle for the 1024-entry v2 exchange buffers ----
__device__ __forceinline__ int swz16(int j) { return j ^ (((j >> 5) & 1) << 2); }

// ---------------- single-qubit lane gate on 1 amp ----------------
template<int VL>
__device__ __forceinline__ void gate1(v2& amp, float4 U0, float4 U1, int lane) {
  float px = lx<VL>(amp.x), py = lx<VL>(amp.y);
  const bool par = (lane & VL) != 0;
  const float Ax = par ? U1.z : U0.x, Ay = par ? U1.w : U0.y;
  const float Bx = par ? U1.x : U0.z, By = par ? U1.y : U0.w;
  v2 res;
  res.x = Ax * amp.x - Ay * amp.y + Bx * px - By * py;
  res.y = Ax * amp.y + Ay * amp.x + Bx * py + By * px;
  amp = res;
}

template<int VL>
__device__ __forceinline__ float xdot1(v2 amp) {
  float px = lx<VL>(amp.x), py = lx<VL>(amp.y);
  return amp.x * px + amp.y * py;
}
__device__ __forceinline__ float vdot1(v2 a, v2 p) { return a.x * p.x + a.y * p.y; }

// ---------------- main kernel: 16 waves per batch element ----------------
__global__ __launch_bounds__(NTHR, 4) void qmamba_main(
    const float* __restrict__ angles, const float* __restrict__ Wx,
    const float* __restrict__ Wdt, const float* __restrict__ bdt,
    const float* __restrict__ pc, const float* __restrict__ cp,
    float* __restrict__ out)
{
  __shared__ float  tblL[SEQ][RECF];   // 73728 B
  __shared__ float4 uuL[40];           // 640 B
  __shared__ v2     ex0[1024];         // 8192 B
  __shared__ v2     ex1[1024];         // 8192 B
  __shared__ v2     cwT[2][16][16];    // 4096 B  wave-gate flat-sum coeffs
  __shared__ float  zbT[16][16];       // 1024 B  [wire][wave] partials

  const int tid  = threadIdx.x;
  const int lane = tid & 63;
  const int wave = tid >> 6;
  const int b    = blockIdx.x;

  // prologue 1: fused variational unitaries U = RZ(g)*RY(be)*RX(al)
  if (tid < 20) {
    int k = tid * 3;
    float al = 0.5f * cp[k], be = 0.5f * cp[k + 1], ga = 0.5f * cp[k + 2];
    float ca = __cosf(al), sa = __sinf(al);
    float cb = __cosf(be), sb = __sinf(be);
    float cg = __cosf(ga), sg = __sinf(ga);
    float2 M00 = make_float2(cb * ca,  sb * sa);
    float2 M01 = make_float2(-sb * ca, -cb * sa);
    float2 M10 = make_float2(sb * ca,  -cb * sa);
    float2 M11 = make_float2(cb * ca,  -sb * sa);
    float2 e0 = make_float2(cg, -sg), e1 = make_float2(cg, sg);
    auto cm = [](float2 a, float2 c) {
      return make_float2(a.x * c.x - a.y * c.y, a.x * c.y + a.y * c.x);
    };
    float2 u00 = cm(M00, e0), u01 = cm(M01, e0), u10 = cm(M10, e1), u11 = cm(M11, e1);
    uuL[2 * tid]     = make_float4(u00.x, u00.y, u01.x, u01.y);
    uuL[2 * tid + 1] = make_float4(u10.x, u10.y, u11.x, u11.y);
  }

  // prologue 2: per-step tables (thread pairs split the 10-wire loop)
  {
    const int t = tid >> 1, half = tid & 1;
    const float* ar = angles + (size_t)(b * SEQ + t) * NQ;
    float a[NQ];
#pragma unroll
    for (int n = 0; n < NQ; ++n) a[n] = ar[n];
    float dtr[5];
#pragma unroll
    for (int r = 0; r < 5; ++r) {
      float acc = 0.f;
#pragma unroll
      for (int n = 0; n < NQ; ++n) acc += a[n] * Wx[r * NQ + n];
      dtr[r] = acc;
    }
    float* rec = &tblL[t][0];
#pragma unroll
    for (int ww = 0; ww < 5; ++ww) {
      const int w = half * 5 + ww;
      float lin = bdt[w];
#pragma unroll
      for (int r = 0; r < 5; ++r) lin += dtr[r] * Wdt[w * 5 + r];
      float sp = lin > 0.f ? lin + log1pf(__expf(-lin)) : log1pf(__expf(lin));
      float th = tanhf(sp) * PIF;
      float fa = a[w] * th;
      rec[w]      = th;
      rec[12 + w] = __cosf(fa);
      rec[24 + w] = __sinf(fa);
    }
  }
  __syncthreads();

  // wave-gate flat-sum coefficient table (reads uuL)
  if (tid < 512) {
    const int layer = tid >> 8, wv = (tid >> 4) & 15, v = tid & 15;
    const int s5 = wv & 1, s1 = (wv >> 1) & 1, s3 = (wv >> 2) & 1, s7 = (wv >> 3) & 1;
    const int v5 = v & 1, v1 = (v >> 1) & 1, v3 = (v >> 2) & 1, v7 = (v >> 3) & 1;
    auto ent = [&](int g, int row, int col) -> v2 {
      float4 R = uuL[2 * g + row];
      return col ? v2{R.z, R.w} : v2{R.x, R.y};
    };
    auto cmul = [](v2 a, v2 c) -> v2 {
      return v2{a.x * c.x - a.y * c.y, a.x * c.y + a.y * c.x};
    };
    v2 c = ent(layer * 10 + 5, s5, s5 ^ v5);
    c = cmul(c, ent(layer * 10 + 1, s1, s1 ^ v1));
    c = cmul(c, ent(layer * 10 + 3, s3, s3 ^ v3));
    c = cmul(c, ent(layer * 10 + 7, s7, s7 ^ v7));
    cwT[layer][wv][v] = c;
  }
  __syncthreads();

  // Phase-B hoist: S(t) = sum_i K_i * tha_i(t); K_i static per thread.
  // Sign convention (verified R7/R9): parity 1 -> +, parity 0 -> -.
  float pch[4];
#pragma unroll
  for (int d = 0; d < 4; ++d) pch[d] = 0.5f * pc[d] * PIF;
  float Ki[NQ];
#pragma unroll
  for (int i = 0; i < NQ; ++i) {
    float k = 0.f;
#pragma unroll
    for (int d = 0; d < 4; ++d) {
      const int m  = CT.mz[d][i];
      const int lm = lanePart(m), wm = wavePart16(m);
      const int par = (__popc(lane & lm) ^ __popc(wave & wm)) & 1;
      k += par ? pch[d] : -pch[d];
    }
    Ki[i] = k;
  }

  // permutation write bases (image of this thread's lane+wave bits)
  int d4 = 0, dL = 0;
  if (lane & 1)  { d4 ^= PC.c4[0]; dL ^= PC.cL[0]; }
  if (lane & 2)  { d4 ^= PC.c4[5]; dL ^= PC.cL[5]; }
  if (lane & 4)  { d4 ^= PC.c4[1]; dL ^= PC.cL[1]; }
  if (lane & 8)  { d4 ^= PC.c4[7]; dL ^= PC.cL[7]; }
  if (lane & 16) { d4 ^= PC.c4[3]; dL ^= PC.cL[3]; }
  if (lane & 32) { d4 ^= PC.c4[9]; dL ^= PC.cL[9]; }
  if (wave & 1)  { d4 ^= PC.c4[4]; dL ^= PC.cL[4]; }
  if (wave & 2)  { d4 ^= PC.c4[8]; dL ^= PC.cL[8]; }
  if (wave & 4)  { d4 ^= PC.c4[6]; dL ^= PC.cL[6]; }
  if (wave & 8)  { d4 ^= PC.c4[2]; dL ^= PC.cL[2]; }

  const int oidx = (lane & 1) | (((lane >> 1) & 1) << 5) | (((lane >> 2) & 1) << 1)
                 | (((lane >> 3) & 1) << 7) | (((lane >> 4) & 1) << 3) | (((lane >> 5) & 1) << 9)
                 | ((wave & 1) << 4) | (((wave >> 1) & 1) << 8)
                 | (((wave >> 2) & 1) << 6) | (((wave >> 3) & 1) << 2);

  // precomputed swizzled addresses (loop-invariant)
  const int w4 = swz16(d4), wL = swz16(dL);
  int rofs[16];
#pragma unroll
  for (int v = 0; v < 16; ++v) rofs[v] = swz16(oidx ^ VOFS16[v]);

  float hcw[NQ], hsw[NQ];
#pragma unroll
  for (int w = 0; w < NQ; ++w) { hcw[w] = 1.f; hsw[w] = 0.f; }

  v2 amp;

#pragma unroll 1
  for (int t = 0; t < SEQ; ++t) {
    float tha[12];
    {
      const float4* rq = (const float4*)&tblL[t][0];
#pragma unroll
      for (int j = 0; j < 3; ++j) ((float4*)tha)[j] = rq[j];
    }

    // ---- Phase A: real product state from RY(h)|0>
    float F;
    F  = (lane & 1)  ? hsw[9] : hcw[9];
    F *= (lane & 2)  ? hsw[4] : hcw[4];
    F *= (lane & 4)  ? hsw[8] : hcw[8];
    F *= (lane & 8)  ? hsw[2] : hcw[2];
    F *= (lane & 16) ? hsw[6] : hcw[6];
    F *= (lane & 32) ? hsw[0] : hcw[0];
    F *= (wave & 1)  ? hsw[5] : hcw[5];
    F *= (wave & 2)  ? hsw[1] : hcw[1];
    F *= (wave & 4)  ? hsw[3] : hcw[3];
    F *= (wave & 8)  ? hsw[7] : hcw[7];

    // ---- Phase B: hoisted 40-RZ phase = 10 FMAs
    float S = 0.f;
#pragma unroll
    for (int i = 0; i < NQ; ++i) S += Ki[i] * tha[i];
    {
      float sn, cs;
      __sincosf(S, &sn, &cs);
      amp.x = F * cs; amp.y = F * sn;
    }

    // ---- P4 permute merged with layer-0 wave gates (wires 5,1,3,7) ----
    ex0[w4] = amp;
    __syncthreads();
    {
      v2 acc = {0.f, 0.f};
#pragma unroll
      for (int v = 0; v < 16; ++v) {
        v2 p = ex0[rofs[v]];
        v2 c = cwT[0][wave][v];
        acc.x += c.x * p.x - c.y * p.y;
        acc.y += c.x * p.y + c.y * p.x;
      }
      amp = acc;
    }
    // layer-0 local gates (wires 9,4,8,2,6,0)
    gate1<1> (amp, uuL[18], uuL[19], lane);
    gate1<2> (amp, uuL[8],  uuL[9],  lane);
    gate1<4> (amp, uuL[16], uuL[17], lane);
    gate1<8> (amp, uuL[4],  uuL[5],  lane);
    gate1<16>(amp, uuL[12], uuL[13], lane);
    gate1<32>(amp, uuL[0],  uuL[1],  lane);

    // ---- PL permute merged with layer-1 wave gates ----
    ex1[wL] = amp;
    __syncthreads();
    {
      v2 acc = {0.f, 0.f};
#pragma unroll
      for (int v = 0; v < 16; ++v) {
        v2 p = ex1[rofs[v]];
        v2 c = cwT[1][wave][v];
        acc.x += c.x * p.x - c.y * p.y;
        acc.y += c.x * p.y + c.y * p.x;
      }
      amp = acc;
    }
    // layer-1 local gates
    gate1<1> (amp, uuL[38], uuL[39], lane);
    gate1<2> (amp, uuL[28], uuL[29], lane);
    gate1<4> (amp, uuL[36], uuL[37], lane);
    gate1<8> (amp, uuL[24], uuL[25], lane);
    gate1<16>(amp, uuL[32], uuL[33], lane);
    gate1<32>(amp, uuL[20], uuL[21], lane);

    // ---- final PL permute merged with measurement ----
    ex0[wL] = amp;
    __syncthreads();
    amp      = ex0[rofs[0]];
    v2 p5    = ex0[rofs[1]];    // ^ phys4  (wire 5)
    v2 p1    = ex0[rofs[2]];    // ^ phys8  (wire 1)
    v2 p3    = ex0[rofs[4]];    // ^ phys6  (wire 3)
    v2 p7    = ex0[rofs[8]];    // ^ phys2  (wire 7)

    float cfv[12], sfv[12];
    {
      const float4* rq = (const float4*)&tblL[t][0];
#pragma unroll
      for (int j = 0; j < 3; ++j) { ((float4*)cfv)[j] = rq[3 + j]; ((float4*)sfv)[j] = rq[6 + j]; }
    }

    const float n = amp.x * amp.x + amp.y * amp.y;

    float zv[NQ];
    { float zp = (lane & 32) ? -n : n; zv[0] = cfv[0] * zp - sfv[0] * xdot1<32>(amp); }
    { float zp = (wave & 2)  ? -n : n; zv[1] = cfv[1] * zp - sfv[1] * vdot1(amp, p1); }
    { float zp = (lane & 8)  ? -n : n; zv[2] = cfv[2] * zp - sfv[2] * xdot1<8>(amp); }
    { float zp = (wave & 4)  ? -n : n; zv[3] = cfv[3] * zp - sfv[3] * vdot1(amp, p3); }
    { float zp = (lane & 2)  ? -n : n; zv[4] = cfv[4] * zp - sfv[4] * xdot1<2>(amp); }
    { float zp = (wave & 1)  ? -n : n; zv[5] = cfv[5] * zp - sfv[5] * vdot1(amp, p5); }
    { float zp = (lane & 16) ? -n : n; zv[6] = cfv[6] * zp - sfv[6] * xdot1<16>(amp); }
    { float zp = (wave & 8)  ? -n : n; zv[7] = cfv[7] * zp - sfv[7] * vdot1(amp, p7); }
    { float zp = (lane & 4)  ? -n : n; zv[8] = cfv[8] * zp - sfv[8] * xdot1<4>(amp); }
    { float zp = (lane & 1)  ? -n : n; zv[9] = cfv[9] * zp - sfv[9] * xdot1<1>(amp); }

    // per-wave lane reduction: 3 DPP stages + pack + 3 stages -> lane w = partial z_w
#pragma unroll
    for (int w = 0; w < NQ; ++w) {
      zv[w] += lx<1>(zv[w]);
      zv[w] += lx<2>(zv[w]);
      zv[w] += lx<4>(zv[w]);
    }
    const int l7 = lane & 7;
    float c01 = (l7 & 1) ? zv[1] : zv[0];
    float c23 = (l7 & 1) ? zv[3] : zv[2];
    float c45 = (l7 & 1) ? zv[5] : zv[4];
    float c67 = (l7 & 1) ? zv[7] : zv[6];
    float c03 = (l7 & 2) ? c23 : c01;
    float c47 = (l7 & 2) ? c67 : c45;
    float pk  = (l7 & 4) ? c47 : c03;
    pk += lx<8>(pk);  pk += lx<16>(pk);  pk += lx<32>(pk);
    float z8 = zv[8]; z8 += lx<8>(z8); z8 += lx<16>(z8); z8 += lx<32>(z8);
    float z9 = zv[9]; z9 += lx<8>(z9); z9 += lx<16>(z9); z9 += lx<32>(z9);
    float zsel = pk;
    zsel = (lane == 8) ? z8 : zsel;
    zsel = (lane == 9) ? z9 : zsel;

    // cross-wave combine + raw z store + h for next step
    if (lane < NQ) zbT[lane][wave] = zsel;
    __syncthreads();
    float z = 0.f;
    if (lane < NQ) {
      const float4* zr = (const float4*)&zbT[lane][0];
      float4 q0 = zr[0], q1 = zr[1], q2 = zr[2], q3 = zr[3];
      z = ((q0.x + q0.y) + (q0.z + q0.w)) + ((q1.x + q1.y) + (q1.z + q1.w))
        + ((q2.x + q2.y) + (q2.z + q2.w)) + ((q3.x + q3.y) + (q3.z + q3.w));
      if (wave == 0) out[(size_t)(b * SEQ + t) * NQ + lane] = z;
    }
    float sn_h, cs_h;
    __sincosf(0.5f * z, &sn_h, &cs_h);
#pragma unroll
    for (int w = 0; w < NQ; ++w) { hcw[w] = rdl(cs_h, w); hsw[w] = rdl(sn_h, w); }
  }
}

// ---------------- post kernel: out = C*z + D*a, in place ----------------
__global__ __launch_bounds__(256) void qmamba_post(
    const float* __restrict__ angles, const float* __restrict__ Wx,
    const float* __restrict__ Dg, float* __restrict__ out)
{
  int i = blockIdx.x * 256 + threadIdx.x;          // 0 .. 128*512*10-1
  if (i >= NB * SEQ * NQ) return;
  int w  = i % NQ;
  int bt = i / NQ;
  const float* a = angles + (size_t)bt * NQ;
  float C = 0.f;
#pragma unroll
  for (int n = 0; n < NQ; ++n) C += a[n] * Wx[(15 + w) * NQ + n];
  float z = out[i];
  out[i] = C * z + Dg[w] * a[w];
}

extern "C" void kernel_launch(void* const* d_in, const int* in_sizes, int n_in,
                              void* d_out, int out_size, void* d_ws, size_t ws_size,
                              hipStream_t stream) {
  (void)in_sizes; (void)n_in; (void)out_size; (void)d_ws; (void)ws_size;
  const float* angles = (const float*)d_in[0];
  const float* Wx     = (const float*)d_in[1];
  const float* Wdt    = (const float*)d_in[2];
  const float* bdt    = (const float*)d_in[3];
  const float* pc     = (const float*)d_in[4];
  const float* cp     = (const float*)d_in[5];
  const float* Dg     = (const float*)d_in[6];
  float* out = (float*)d_out;
  hipLaunchKernelGGL(qmamba_main, dim3(NB), dim3(NTHR), 0, stream,
                     angles, Wx, Wdt, bdt, pc, cp, out);
  hipLaunchKernelGGL(qmamba_post, dim3((NB * SEQ * NQ + 255) / 256), dim3(256), 0, stream,
                     angles, Wx, Dg, out);
}